// Round 1
// baseline (13850.735 us; speedup 1.0000x reference)
//
#include <hip/hip_runtime.h>

// ---------------------------------------------------------------------------
// CorrelationalDetector: 5-layer conv encoder (shared weights) on crop+frame,
// per-sample cross-correlation, BatchNorm(1).
// Round 1: correct fp32 baseline. Direct conv, 1x4 outputs per thread.
// ---------------------------------------------------------------------------

template<int S, bool RELU>
__global__ __launch_bounds__(256)
void conv3x3_k(const float* __restrict__ in, const float* __restrict__ wgt,
               const float* __restrict__ bias, float* __restrict__ out,
               int B, int IC, int OC, int IH, int IW, int OH, int OW)
{
    const int OW4 = (OW + 3) >> 2;
    const int total = B * OC * OH * OW4;
    for (int idx = blockIdx.x * blockDim.x + threadIdx.x; idx < total;
         idx += gridDim.x * blockDim.x) {
        int t = idx;
        const int ow4 = t % OW4; t /= OW4;
        const int oh  = t % OH;  t /= OH;
        const int oc  = t % OC;  const int b = t / OC;
        const int owb = ow4 * 4;

        float acc[4];
        const float bval = bias[oc];
        acc[0] = bval; acc[1] = bval; acc[2] = bval; acc[3] = bval;

        const int iy = oh * S - 1;
        const int ix = owb * S - 1;
        const float* __restrict__ inb = in + (size_t)b * IC * IH * IW;
        const float* __restrict__ wb  = wgt + (size_t)oc * IC * 9;

        const bool fast = (iy >= 0) && (iy + 2 < IH) && (ix >= 0) &&
                          ((owb + 3) * S + 1 < IW) && (owb + 3 < OW);
        if (fast) {
            for (int ic = 0; ic < IC; ++ic) {
                const float* __restrict__ wp = wb + ic * 9;
                const float* __restrict__ ip = inb + (size_t)ic * IH * IW
                                             + (size_t)iy * IW + ix;
                #pragma unroll
                for (int r = 0; r < 3; ++r) {
                    const float w0 = wp[r*3+0], w1 = wp[r*3+1], w2 = wp[r*3+2];
                    const float* __restrict__ rp = ip + r * IW;
                    if (S == 1) {
                        const float x0=rp[0], x1=rp[1], x2=rp[2],
                                    x3=rp[3], x4=rp[4], x5=rp[5];
                        acc[0] += w0*x0 + w1*x1 + w2*x2;
                        acc[1] += w0*x1 + w1*x2 + w2*x3;
                        acc[2] += w0*x2 + w1*x3 + w2*x4;
                        acc[3] += w0*x3 + w1*x4 + w2*x5;
                    } else {
                        const float x0=rp[0], x1=rp[1], x2=rp[2], x3=rp[3],
                                    x4=rp[4], x5=rp[5], x6=rp[6], x7=rp[7], x8=rp[8];
                        acc[0] += w0*x0 + w1*x1 + w2*x2;
                        acc[1] += w0*x2 + w1*x3 + w2*x4;
                        acc[2] += w0*x4 + w1*x5 + w2*x6;
                        acc[3] += w0*x6 + w1*x7 + w2*x8;
                    }
                }
            }
        } else {
            for (int ic = 0; ic < IC; ++ic) {
                const float* __restrict__ wp = wb + ic * 9;
                const float* __restrict__ ip = inb + (size_t)ic * IH * IW;
                #pragma unroll
                for (int ky = 0; ky < 3; ++ky) {
                    const int y = iy + ky;
                    if ((unsigned)y >= (unsigned)IH) continue;
                    #pragma unroll
                    for (int kx = 0; kx < 3; ++kx) {
                        const float wv = wp[ky*3+kx];
                        #pragma unroll
                        for (int j = 0; j < 4; ++j) {
                            const int x = (owb + j) * S - 1 + kx;
                            if ((unsigned)x < (unsigned)IW)
                                acc[j] += ip[(size_t)y * IW + x] * wv;
                        }
                    }
                }
            }
        }
        #pragma unroll
        for (int j = 0; j < 4; ++j) {
            const int ow = owb + j;
            if (ow < OW) {
                float v = acc[j];
                if (RELU) v = fmaxf(v, 0.f);
                out[(((size_t)b * OC + oc) * OH + oh) * OW + ow] = v;
            }
        }
    }
}

// Per-sample VALID xcorr: frame_fm [B,256,32,32] (*) crop_fm [B,256,8,8] -> 25x25.
// Split channels into 4 chunks of 64; partial[cc][b][625]; no atomics.
__global__ __launch_bounds__(256)
void xcorr_k(const float* __restrict__ frame_fm, const float* __restrict__ crop_fm,
             float* __restrict__ partial)
{
    const int b  = blockIdx.x;   // 64
    const int cc = blockIdx.y;   // 4
    __shared__ float k_s[64 * 64];   // 64 ch x 8x8 = 16 KiB
    for (int i = threadIdx.x; i < 64 * 64; i += blockDim.x)
        k_s[i] = crop_fm[((size_t)b * 256 + cc * 64) * 64 + i];
    __syncthreads();

    const float* __restrict__ fb = frame_fm + ((size_t)b * 256 + cc * 64) * 1024;
    for (int o = threadIdx.x; o < 625; o += blockDim.x) {
        const int oy = o / 25, ox = o % 25;
        float acc = 0.f;
        for (int c = 0; c < 64; ++c) {
            const float* __restrict__ fp = fb + (size_t)c * 1024 + oy * 32 + ox;
            const float* __restrict__ kp = k_s + c * 64;
            #pragma unroll
            for (int dy = 0; dy < 8; ++dy) {
                #pragma unroll
                for (int dx = 0; dx < 8; ++dx)
                    acc += fp[dy * 32 + dx] * kp[dy * 8 + dx];
            }
        }
        partial[((size_t)cc * 64 + b) * 625 + o] = acc;
    }
}

// Single-block BN: sum 4 partials -> rmap, mean/var over all 40000, normalize.
__global__ __launch_bounds__(1024)
void bn_k(float* __restrict__ partial, const float* __restrict__ gamma,
          const float* __restrict__ beta, float* __restrict__ out)
{
    const int N = 64 * 625;
    const int tid = threadIdx.x;
    __shared__ float rs[1024], rq[1024];
    __shared__ float mean_s, inv_s;

    float s = 0.f, q = 0.f;
    for (int i = tid; i < N; i += blockDim.x) {
        const float v = partial[i] + partial[N + i] + partial[2 * N + i] + partial[3 * N + i];
        partial[i] = v;           // stash rmap for pass 2 (rewritten every call)
        s += v; q += v * v;
    }
    rs[tid] = s; rq[tid] = q;
    __syncthreads();
    for (int off = 512; off > 0; off >>= 1) {
        if (tid < off) { rs[tid] += rs[tid + off]; rq[tid] += rq[tid + off]; }
        __syncthreads();
    }
    if (tid == 0) {
        const float m   = rs[0] / (float)N;
        const float var = rq[0] / (float)N - m * m;
        mean_s = m;
        inv_s  = rsqrtf(var + 1e-5f);
    }
    __syncthreads();
    const float g = gamma[0], bt = beta[0];
    for (int i = tid; i < N; i += blockDim.x)
        out[i] = (partial[i] - mean_s) * inv_s * g + bt;
}

// ---------------------------------------------------------------------------

static inline void launch_conv(hipStream_t stream, const float* in, const float* w,
                               const float* b, float* out, int B, int IC, int OC,
                               int IH, int IW, int OH, int OW, int S, bool relu)
{
    const int OW4 = (OW + 3) >> 2;
    const long total = (long)B * OC * OH * OW4;
    const int blocks = (int)((total + 255) / 256);
    if (S == 1) {
        if (relu) conv3x3_k<1, true ><<<blocks, 256, 0, stream>>>(in, w, b, out, B, IC, OC, IH, IW, OH, OW);
        else      conv3x3_k<1, false><<<blocks, 256, 0, stream>>>(in, w, b, out, B, IC, OC, IH, IW, OH, OW);
    } else {
        if (relu) conv3x3_k<2, true ><<<blocks, 256, 0, stream>>>(in, w, b, out, B, IC, OC, IH, IW, OH, OW);
        else      conv3x3_k<2, false><<<blocks, 256, 0, stream>>>(in, w, b, out, B, IC, OC, IH, IW, OH, OW);
    }
}

extern "C" void kernel_launch(void* const* d_in, const int* in_sizes, int n_in,
                              void* d_out, int out_size, void* d_ws, size_t ws_size,
                              hipStream_t stream)
{
    const float* crop  = (const float*)d_in[0];
    const float* frame = (const float*)d_in[1];
    const float* W[5];
    const float* bb[5];
    for (int i = 0; i < 5; ++i) { W[i] = (const float*)d_in[2 + 2 * i]; bb[i] = (const float*)d_in[3 + 2 * i]; }
    const float* gamma = (const float*)d_in[12];
    const float* beta  = (const float*)d_in[13];
    float* out = (float*)d_out;

    // ws layout (fp32): A (16.78M) | B (8.39M) | crop_fm (1.05M) | partial (160K)
    float* A       = (float*)d_ws;
    float* Bf      = A + 16777216;
    float* cropfm  = Bf + 8388608;
    float* partial = cropfm + 1048576;   // total 26,374,400 floats = 100.6 MiB

    const int B = 64;

    // ---- crop encoder: 64x64 -> 32 -> 16 -> 16 -> 8 -> 8 ----
    launch_conv(stream, crop, W[0], bb[0], A,      B,   3,   3, 64, 64, 32, 32, 2, true);
    launch_conv(stream, A,    W[1], bb[1], Bf,     B,   3,  16, 32, 32, 16, 16, 2, true);
    launch_conv(stream, Bf,   W[2], bb[2], A,      B,  16,  64, 16, 16, 16, 16, 1, true);
    launch_conv(stream, A,    W[3], bb[3], Bf,     B,  64, 128, 16, 16,  8,  8, 2, true);
    launch_conv(stream, Bf,   W[4], bb[4], cropfm, B, 128, 256,  8,  8,  8,  8, 1, false);

    // ---- frame encoder: 256x256 -> 128 -> 64 -> 64 -> 32 -> 32 ----
    launch_conv(stream, frame, W[0], bb[0], A,  B,   3,   3, 256, 256, 128, 128, 2, true);
    launch_conv(stream, A,     W[1], bb[1], Bf, B,   3,  16, 128, 128,  64,  64, 2, true);
    launch_conv(stream, Bf,    W[2], bb[2], A,  B,  16,  64,  64,  64,  64,  64, 1, true);
    launch_conv(stream, A,     W[3], bb[3], Bf, B,  64, 128,  64,  64,  32,  32, 2, true);
    launch_conv(stream, Bf,    W[4], bb[4], A,  B, 128, 256,  32,  32,  32,  32, 1, false);

    // ---- per-sample xcorr + batchnorm ----
    xcorr_k<<<dim3(64, 4), 256, 0, stream>>>(A, cropfm, partial);
    bn_k<<<1, 1024, 0, stream>>>(partial, gamma, beta, out);
}

// Round 2
// 705.090 us; speedup vs baseline: 19.6439x; 19.6439x over previous
//
#include <hip/hip_runtime.h>

// ---------------------------------------------------------------------------
// CorrelationalDetector R2: NHWC bf16 MFMA implicit-GEMM for L2/L3/L4 + xcorr,
// fp32 VALU for L0/L1 (IC=3). Activations NHWC bf16 with zero halo so conv
// taps are pure pointer offsets and every MFMA fragment is one 16B load.
// ---------------------------------------------------------------------------

typedef __bf16 bf16x8 __attribute__((ext_vector_type(8)));
typedef float f32x4 __attribute__((ext_vector_type(4)));
typedef unsigned int u32x4 __attribute__((ext_vector_type(4)));
typedef unsigned int u32x2 __attribute__((ext_vector_type(2)));
typedef unsigned short u16;

__device__ __forceinline__ u16 f2bf(float v) {
    unsigned u = __float_as_uint(v);
    u += 0x7fffu + ((u >> 16) & 1u);          // RNE
    return (u16)(u >> 16);
}

__device__ __forceinline__ bf16x8 ldb8(const u16* p) {
    return *(const bf16x8*)p;                  // 16B aligned by construction
}

// ---- L0: IC=3,OC=3, stride2, NCHW fp32 in -> NHWC fp32 padded out ----------
__global__ __launch_bounds__(256)
void conv0_k(const float* __restrict__ in, const float* __restrict__ W,
             const float* __restrict__ bias, float* __restrict__ outP,
             int Btot, int IH, int IW, int OH, int OW)
{
    const int OWp = OW + 2, OHp = OH + 2;
    const int total = Btot * OH * OW;
    for (int idx = blockIdx.x * blockDim.x + threadIdx.x; idx < total;
         idx += gridDim.x * blockDim.x) {
        const int ow = idx % OW; int t = idx / OW;
        const int oh = t % OH;  const int b = t / OH;
        float a0 = bias[0], a1 = bias[1], a2 = bias[2];
        const float* inb = in + (size_t)b * 3 * IH * IW;
        for (int ic = 0; ic < 3; ++ic) {
            const float* ip = inb + (size_t)ic * IH * IW;
            #pragma unroll
            for (int ky = 0; ky < 3; ++ky) {
                const int y = oh * 2 - 1 + ky;
                if ((unsigned)y >= (unsigned)IH) continue;
                #pragma unroll
                for (int kx = 0; kx < 3; ++kx) {
                    const int x = ow * 2 - 1 + kx;
                    if ((unsigned)x >= (unsigned)IW) continue;
                    const float v = ip[(size_t)y * IW + x];
                    const int wi = ic * 9 + ky * 3 + kx;
                    a0 += v * W[wi]; a1 += v * W[27 + wi]; a2 += v * W[54 + wi];
                }
            }
        }
        float* op = outP + (((size_t)b * OHp + oh + 1) * OWp + ow + 1) * 3;
        op[0] = fmaxf(a0, 0.f); op[1] = fmaxf(a1, 0.f); op[2] = fmaxf(a2, 0.f);
    }
}

// ---- L1: IC=3,OC=16, stride2, NHWC fp32 padded in -> NHWC bf16 padded out --
__global__ __launch_bounds__(256)
void conv1_k(const float* __restrict__ inP, const float* __restrict__ W,
             const float* __restrict__ bias, u16* __restrict__ outP,
             int Btot, int IHp, int IWp, int OH, int OW)
{
    const int OWp = OW + 2, OHp = OH + 2;
    const int total = Btot * OH * OW;
    for (int idx = blockIdx.x * blockDim.x + threadIdx.x; idx < total;
         idx += gridDim.x * blockDim.x) {
        const int ow = idx % OW; int t = idx / OW;
        const int oh = t % OH;  const int b = t / OH;
        float acc[16];
        #pragma unroll
        for (int oc = 0; oc < 16; ++oc) acc[oc] = bias[oc];
        const float* ib = inP + (size_t)b * IHp * IWp * 3;
        #pragma unroll
        for (int ky = 0; ky < 3; ++ky) {
            #pragma unroll
            for (int kx = 0; kx < 3; ++kx) {
                const float* p = ib + (((size_t)(oh * 2 + ky)) * IWp + (ow * 2 + kx)) * 3;
                const float x0 = p[0], x1 = p[1], x2 = p[2];
                const float* wp = W + ky * 3 + kx;       // W[oc*27 + ic*9 + tap]
                #pragma unroll
                for (int oc = 0; oc < 16; ++oc)
                    acc[oc] += x0 * wp[oc * 27] + x1 * wp[oc * 27 + 9] + x2 * wp[oc * 27 + 18];
            }
        }
        u16* op = outP + (((size_t)b * OHp + oh + 1) * OWp + ow + 1) * 16;
        #pragma unroll
        for (int oc = 0; oc < 16; ++oc) op[oc] = f2bf(fmaxf(acc[oc], 0.f));
    }
}

// ---- weight pack: OIHW fp32 -> [oc][Kpad] bf16, k = tap*IC + ic ------------
__global__ __launch_bounds__(256)
void packw_k(const float* __restrict__ W, u16* __restrict__ Wp,
             int OC, int IC, int Kpad)
{
    const int total = OC * Kpad;
    for (int idx = blockIdx.x * blockDim.x + threadIdx.x; idx < total;
         idx += gridDim.x * blockDim.x) {
        const int k = idx % Kpad, oc = idx / Kpad;
        const int tap = k / IC, ic = k % IC;
        const float v = (tap < 9) ? W[((size_t)oc * IC + ic) * 9 + tap] : 0.f;
        Wp[idx] = f2bf(v);
    }
}

// ---- MFMA implicit-GEMM conv3x3 (pad=1), NHWC bf16 halo in/out -------------
// wave tile: 64 oc x 32 px; K = 9*IC (padded to mult of 32).
template<int S>
__global__ __launch_bounds__(256)
void convmf_k(const u16* __restrict__ inP, const u16* __restrict__ Wp,
              const float* __restrict__ bias, u16* __restrict__ out,
              int IC, int IWp, int inSS,
              int OH, int OW, int OWp_o, int outSS, int pad_o,
              int Kpad, int relu, int n_mt, int n_pt)
{
    const int w    = blockIdx.x * 4 + (threadIdx.x >> 6);
    const int lane = threadIdx.x & 63;
    const int lr   = lane & 15, lg = lane >> 4;
    const int tilesPerB = n_mt * n_pt;
    const int b  = w / tilesPerB;
    const int r  = w - b * tilesPerB;
    const int mt = r / n_pt;
    const int pt = r - mt * n_pt;
    const int ocb = mt * 64;

    const int pe0 = pt * 32 + lr, pe1 = pe0 + 16;
    const int oh0 = pe0 / OW, ow0 = pe0 - oh0 * OW;
    const int oh1 = pe1 / OW, ow1 = pe1 - oh1 * OW;

    const u16* in0 = inP + (size_t)b * inSS + ((size_t)(oh0 * S) * IWp + ow0 * S) * IC;
    const u16* in1 = inP + (size_t)b * inSS + ((size_t)(oh1 * S) * IWp + ow1 * S) * IC;
    const u16* wrow[4];
    #pragma unroll
    for (int mf = 0; mf < 4; ++mf)
        wrow[mf] = Wp + (size_t)(ocb + mf * 16 + lr) * Kpad + lg * 8;

    f32x4 acc[4][2] = {};

    if ((IC & 31) == 0) {
        // IC multiple of 32: tap uniform across the wave per k-step
        for (int tap = 0; tap < 9; ++tap) {
            const int ky = (tap * 11) >> 5, kx = tap - 3 * ky;
            const u16* p0 = in0 + ((size_t)ky * IWp + kx) * IC + lg * 8;
            const u16* p1 = in1 + ((size_t)ky * IWp + kx) * IC + lg * 8;
            const int kb = tap * IC;
            for (int icb = 0; icb < IC; icb += 32) {
                const bf16x8 bv0 = ldb8(p0 + icb);
                const bf16x8 bv1 = ldb8(p1 + icb);
                #pragma unroll
                for (int mf = 0; mf < 4; ++mf) {
                    const bf16x8 av = ldb8(wrow[mf] + kb + icb);
                    acc[mf][0] = __builtin_amdgcn_mfma_f32_16x16x32_bf16(av, bv0, acc[mf][0], 0, 0, 0);
                    acc[mf][1] = __builtin_amdgcn_mfma_f32_16x16x32_bf16(av, bv1, acc[mf][1], 0, 0, 0);
                }
            }
        }
    } else {
        // IC == 16: one k-step spans 2 taps; per-lane tap/ic
        for (int kb = 0; kb < Kpad; kb += 32) {
            const int kt = kb + lg * 8;
            int tap = kt >> 4;
            if (tap > 8) tap = 8;                     // padded k, weight is 0
            const int ic = kt & 15;
            const int ky = (tap * 11) >> 5, kx = tap - 3 * ky;
            const size_t off = ((size_t)ky * IWp + kx) * 16 + ic;
            const bf16x8 bv0 = ldb8(in0 + off);
            const bf16x8 bv1 = ldb8(in1 + off);
            #pragma unroll
            for (int mf = 0; mf < 4; ++mf) {
                const bf16x8 av = ldb8(wrow[mf] + kb);
                acc[mf][0] = __builtin_amdgcn_mfma_f32_16x16x32_bf16(av, bv0, acc[mf][0], 0, 0, 0);
                acc[mf][1] = __builtin_amdgcn_mfma_f32_16x16x32_bf16(av, bv1, acc[mf][1], 0, 0, 0);
            }
        }
    }

    // epilogue: D col = lane&15 (pixel), row = lg*4 + reg (oc)
    #pragma unroll
    for (int mf = 0; mf < 4; ++mf) {
        const int oc0 = ocb + mf * 16 + lg * 4;
        const float* bp = bias + oc0;
        const float b0 = bp[0], b1 = bp[1], b2 = bp[2], b3 = bp[3];
        #pragma unroll
        for (int nf = 0; nf < 2; ++nf) {
            const int oh = nf ? oh1 : oh0, ow = nf ? ow1 : ow0;
            const f32x4 a = acc[mf][nf];
            float v0 = a[0] + b0, v1 = a[1] + b1, v2 = a[2] + b2, v3 = a[3] + b3;
            if (relu) {
                v0 = fmaxf(v0, 0.f); v1 = fmaxf(v1, 0.f);
                v2 = fmaxf(v2, 0.f); v3 = fmaxf(v3, 0.f);
            }
            u32x2 pk;
            pk[0] = (unsigned)f2bf(v0) | ((unsigned)f2bf(v1) << 16);
            pk[1] = (unsigned)f2bf(v2) | ((unsigned)f2bf(v3) << 16);
            u16* op = out + (size_t)b * outSS +
                      (((size_t)(oh + pad_o)) * OWp_o + (ow + pad_o)) * 256 / 256;
            // recompute cleanly (avoid accidental optimization above):
            op = out + (size_t)b * outSS +
                 (((size_t)(oh + pad_o)) * OWp_o + (ow + pad_o)) * (size_t)(n_mt * 64) + oc0;
            *(u32x2*)op = pk;
        }
    }
}

// ---- per-sample xcorr, bf16 in, fp32 out -----------------------------------
__global__ __launch_bounds__(128)
void xcorr_k(const u16* __restrict__ ffm, const u16* __restrict__ cfm,
             float* __restrict__ partial)
{
    const int b = blockIdx.x;        // 64
    const int chunk = blockIdx.y;    // 5 chunks of 125 outputs
    __shared__ u16 ks[16384];        // crop_fm[b]: 8*8*256 bf16 = 32KB
    const u16* cb = cfm + (size_t)b * 16384;
    for (int i = threadIdx.x * 8; i < 16384; i += 128 * 8)
        *(u32x4*)&ks[i] = *(const u32x4*)&cb[i];
    __syncthreads();
    const int t = threadIdx.x;
    if (t >= 125) return;
    const int o = chunk * 125 + t;
    const int oy = o / 25, ox = o - oy * 25;
    const u16* fb = ffm + (size_t)b * 262144;
    float acc = 0.f;
    for (int dy = 0; dy < 8; ++dy) {
        const u16* frow = fb + ((size_t)(oy + dy) * 32 + ox) * 256;
        const u16* krow = ks + dy * 8 * 256;
        for (int dx = 0; dx < 8; ++dx) {
            const u32x4* fp = (const u32x4*)(frow + dx * 256);
            const u32x4* kp = (const u32x4*)(krow + dx * 256);
            #pragma unroll 8
            for (int c = 0; c < 32; ++c) {
                const u32x4 fv = fp[c], kv = kp[c];
                #pragma unroll
                for (int j = 0; j < 4; ++j) {
                    const float fl = __uint_as_float(fv[j] << 16);
                    const float fh = __uint_as_float(fv[j] & 0xffff0000u);
                    const float kl = __uint_as_float(kv[j] << 16);
                    const float kh = __uint_as_float(kv[j] & 0xffff0000u);
                    acc = fmaf(fl, kl, acc);
                    acc = fmaf(fh, kh, acc);
                }
            }
        }
    }
    partial[(size_t)b * 625 + o] = acc;
}

// ---- BatchNorm over all 40000 elements -------------------------------------
__global__ __launch_bounds__(1024)
void bn_k(const float* __restrict__ rmap, const float* __restrict__ gamma,
          const float* __restrict__ beta, float* __restrict__ out)
{
    const int N = 40000;
    const int tid = threadIdx.x;
    __shared__ float rs[1024], rq[1024];
    __shared__ float mean_s, inv_s;
    float s = 0.f, q = 0.f;
    for (int i = tid; i < N; i += 1024) {
        const float v = rmap[i];
        s += v; q += v * v;
    }
    rs[tid] = s; rq[tid] = q;
    __syncthreads();
    for (int off = 512; off > 0; off >>= 1) {
        if (tid < off) { rs[tid] += rs[tid + off]; rq[tid] += rq[tid + off]; }
        __syncthreads();
    }
    if (tid == 0) {
        const float m = rs[0] / (float)N;
        mean_s = m;
        inv_s = rsqrtf(rq[0] / (float)N - m * m + 1e-5f);
    }
    __syncthreads();
    const float g = gamma[0], bt = beta[0];
    for (int i = tid; i < N; i += 1024)
        out[i] = (rmap[i] - mean_s) * inv_s * g + bt;
}

// ---------------------------------------------------------------------------

extern "C" void kernel_launch(void* const* d_in, const int* in_sizes, int n_in,
                              void* d_out, int out_size, void* d_ws, size_t ws_size,
                              hipStream_t stream)
{
    (void)in_sizes; (void)n_in; (void)out_size; (void)ws_size;
    const float* crop  = (const float*)d_in[0];
    const float* frame = (const float*)d_in[1];
    const float* W[5]; const float* bb[5];
    for (int i = 0; i < 5; ++i) { W[i] = (const float*)d_in[2 + 2*i]; bb[i] = (const float*)d_in[3 + 2*i]; }
    const float* gamma = (const float*)d_in[12];
    const float* beta  = (const float*)d_in[13];
    float* out = (float*)d_out;

    unsigned char* ws = (unsigned char*)d_ws;
    // byte offsets (regions R1/R2 reused across pipeline stages)
    float* f0p   = (float*)(ws + 0);           // [64][130][130][3] f32  (dead after fL1)
    u16*   f1p   = (u16*)(ws + 12979200);      // [64][66][66][16] bf16  (dead after fL2)
    u16*   f3p   = (u16*)(ws + 0);             // [64][34][34][128] bf16 (aliases f0p+f1p)
    u16*   f2p   = (u16*)(ws + 21900288);      // [64][66][66][64] bf16  (dead after fL3)
    u16*   ffm   = (u16*)(ws + 21900288);      // [64][32][32][256] bf16 (aliases f2p)
    float* c0p   = (float*)(ws + 57584640);    // [64][34][34][3] f32
    u16*   c1p   = (u16*)(ws + 58472448);      // [64][18][18][16]
    u16*   c2p   = (u16*)(ws + 59136000);      // [64][18][18][64]
    u16*   c3p   = (u16*)(ws + 61790208);      // [64][10][10][128]
    u16*   cfm   = (u16*)(ws + 63428608);      // [64][8][8][256]
    u16*   Wp2   = (u16*)(ws + 65525760);      // [64][160]
    u16*   Wp3   = (u16*)(ws + 65546240);      // [128][576]
    u16*   Wp4   = (u16*)(ws + 65693696);      // [256][1152]
    float* part  = (float*)(ws + 66283520);    // [40000]

    // zero halos (and scratch) — must be per-call (ws poisoned before timing)
    hipMemsetAsync(ws + 0,        0, 21900288, stream);   // f0p+f1p
    hipMemsetAsync(ws + 21900288, 0, 35684352, stream);   // f2p
    hipMemsetAsync(ws + 57584640, 0, 5843968,  stream);   // c0p..c3p

    // pack weights to bf16 [oc][Kpad]
    packw_k<<<40,   256, 0, stream>>>(W[2], Wp2,  64,  16,  160);
    packw_k<<<288,  256, 0, stream>>>(W[3], Wp3, 128,  64,  576);
    packw_k<<<1152, 256, 0, stream>>>(W[4], Wp4, 256, 128, 1152);

    // ---- crop encoder ----
    conv0_k<<<256, 256, 0, stream>>>(crop, W[0], bb[0], c0p, 64, 64, 64, 32, 32);
    conv1_k<<<64,  256, 0, stream>>>(c0p, W[1], bb[1], c1p, 64, 34, 34, 16, 16);
    convmf_k<1><<<128, 256, 0, stream>>>(c1p, Wp2, bb[2], c2p,  16, 18,  5184, 16, 16, 18, 20736, 1,  160, 1, 1, 8);
    convmf_k<2><<<64,  256, 0, stream>>>(c2p, Wp3, bb[3], c3p,  64, 18, 20736,  8,  8, 10, 12800, 1,  576, 1, 2, 2);
    convmf_k<1><<<128, 256, 0, stream>>>(c3p, Wp4, bb[4], cfm, 128, 10, 12800,  8,  8,  8, 16384, 0, 1152, 0, 4, 2);

    // ---- frame encoder ----
    conv0_k<<<4096, 256, 0, stream>>>(frame, W[0], bb[0], f0p, 64, 256, 256, 128, 128);
    conv1_k<<<1024, 256, 0, stream>>>(f0p, W[1], bb[1], f1p, 64, 130, 130, 64, 64);
    convmf_k<1><<<2048, 256, 0, stream>>>(f1p, Wp2, bb[2], f2p,  16, 66,  69696, 64, 64, 66, 278784, 1,  160, 1, 1, 128);
    hipMemsetAsync(ws + 0, 0, 18939904, stream);          // f3p halo (f0p/f1p dead)
    convmf_k<2><<<1024, 256, 0, stream>>>(f2p, Wp3, bb[3], f3p,  64, 66, 278784, 32, 32, 34, 147968, 1,  576, 1, 2, 32);
    convmf_k<1><<<2048, 256, 0, stream>>>(f3p, Wp4, bb[4], ffm, 128, 34, 147968, 32, 32, 32, 262144, 0, 1152, 0, 4, 32);

    // ---- xcorr + BN ----
    xcorr_k<<<dim3(64, 5), 128, 0, stream>>>(ffm, cfm, part);
    bn_k<<<1, 1024, 0, stream>>>(part, gamma, beta, out);
}

// Round 3
// 524.021 us; speedup vs baseline: 26.4316x; 1.3455x over previous
//
#include <hip/hip_runtime.h>

// ---------------------------------------------------------------------------
// CorrelationalDetector R3: xcorr as batched MFMA GEMM.
// Per sample b: R[d][(y,ox)] = dot_2048(crop_row_d, frame_row_slice(y,ox));
// rmap[oy][ox] = sum_d R[d][(oy+d,ox)].  Both GEMM fragments are contiguous
// 16B loads in NHWC. Convs unchanged from R2.
// ---------------------------------------------------------------------------

typedef __bf16 bf16x8 __attribute__((ext_vector_type(8)));
typedef float f32x4 __attribute__((ext_vector_type(4)));
typedef unsigned int u32x4 __attribute__((ext_vector_type(4)));
typedef unsigned int u32x2 __attribute__((ext_vector_type(2)));
typedef unsigned short u16;

__device__ __forceinline__ u16 f2bf(float v) {
    unsigned u = __float_as_uint(v);
    u += 0x7fffu + ((u >> 16) & 1u);          // RNE
    return (u16)(u >> 16);
}

__device__ __forceinline__ bf16x8 ldb8(const u16* p) {
    return *(const bf16x8*)p;                  // 16B aligned by construction
}

__device__ __forceinline__ bf16x8 zerob8() {
    u32x4 z = {0u, 0u, 0u, 0u};
    bf16x8 r;
    __builtin_memcpy(&r, &z, 16);
    return r;
}

// ---- L0: IC=3,OC=3, stride2, NCHW fp32 in -> NHWC fp32 padded out ----------
__global__ __launch_bounds__(256)
void conv0_k(const float* __restrict__ in, const float* __restrict__ W,
             const float* __restrict__ bias, float* __restrict__ outP,
             int Btot, int IH, int IW, int OH, int OW)
{
    const int OWp = OW + 2, OHp = OH + 2;
    const int total = Btot * OH * OW;
    for (int idx = blockIdx.x * blockDim.x + threadIdx.x; idx < total;
         idx += gridDim.x * blockDim.x) {
        const int ow = idx % OW; int t = idx / OW;
        const int oh = t % OH;  const int b = t / OH;
        float a0 = bias[0], a1 = bias[1], a2 = bias[2];
        const float* inb = in + (size_t)b * 3 * IH * IW;
        for (int ic = 0; ic < 3; ++ic) {
            const float* ip = inb + (size_t)ic * IH * IW;
            #pragma unroll
            for (int ky = 0; ky < 3; ++ky) {
                const int y = oh * 2 - 1 + ky;
                if ((unsigned)y >= (unsigned)IH) continue;
                #pragma unroll
                for (int kx = 0; kx < 3; ++kx) {
                    const int x = ow * 2 - 1 + kx;
                    if ((unsigned)x >= (unsigned)IW) continue;
                    const float v = ip[(size_t)y * IW + x];
                    const int wi = ic * 9 + ky * 3 + kx;
                    a0 += v * W[wi]; a1 += v * W[27 + wi]; a2 += v * W[54 + wi];
                }
            }
        }
        float* op = outP + (((size_t)b * OHp + oh + 1) * OWp + ow + 1) * 3;
        op[0] = fmaxf(a0, 0.f); op[1] = fmaxf(a1, 0.f); op[2] = fmaxf(a2, 0.f);
    }
}

// ---- L1: IC=3,OC=16, stride2, NHWC fp32 padded in -> NHWC bf16 padded out --
__global__ __launch_bounds__(256)
void conv1_k(const float* __restrict__ inP, const float* __restrict__ W,
             const float* __restrict__ bias, u16* __restrict__ outP,
             int Btot, int IHp, int IWp, int OH, int OW)
{
    const int OWp = OW + 2, OHp = OH + 2;
    const int total = Btot * OH * OW;
    for (int idx = blockIdx.x * blockDim.x + threadIdx.x; idx < total;
         idx += gridDim.x * blockDim.x) {
        const int ow = idx % OW; int t = idx / OW;
        const int oh = t % OH;  const int b = t / OH;
        float acc[16];
        #pragma unroll
        for (int oc = 0; oc < 16; ++oc) acc[oc] = bias[oc];
        const float* ib = inP + (size_t)b * IHp * IWp * 3;
        #pragma unroll
        for (int ky = 0; ky < 3; ++ky) {
            #pragma unroll
            for (int kx = 0; kx < 3; ++kx) {
                const float* p = ib + (((size_t)(oh * 2 + ky)) * IWp + (ow * 2 + kx)) * 3;
                const float x0 = p[0], x1 = p[1], x2 = p[2];
                const float* wp = W + ky * 3 + kx;       // W[oc*27 + ic*9 + tap]
                #pragma unroll
                for (int oc = 0; oc < 16; ++oc)
                    acc[oc] += x0 * wp[oc * 27] + x1 * wp[oc * 27 + 9] + x2 * wp[oc * 27 + 18];
            }
        }
        u16* op = outP + (((size_t)b * OHp + oh + 1) * OWp + ow + 1) * 16;
        #pragma unroll
        for (int oc = 0; oc < 16; ++oc) op[oc] = f2bf(fmaxf(acc[oc], 0.f));
    }
}

// ---- weight pack: OIHW fp32 -> [oc][Kpad] bf16, k = tap*IC + ic ------------
__global__ __launch_bounds__(256)
void packw_k(const float* __restrict__ W, u16* __restrict__ Wp,
             int OC, int IC, int Kpad)
{
    const int total = OC * Kpad;
    for (int idx = blockIdx.x * blockDim.x + threadIdx.x; idx < total;
         idx += gridDim.x * blockDim.x) {
        const int k = idx % Kpad, oc = idx / Kpad;
        const int tap = k / IC, ic = k % IC;
        const float v = (tap < 9) ? W[((size_t)oc * IC + ic) * 9 + tap] : 0.f;
        Wp[idx] = f2bf(v);
    }
}

// ---- MFMA implicit-GEMM conv3x3 (pad=1), NHWC bf16 halo in/out -------------
// wave tile: 64 oc x 32 px; K = 9*IC (padded to mult of 32).
template<int S>
__global__ __launch_bounds__(256)
void convmf_k(const u16* __restrict__ inP, const u16* __restrict__ Wp,
              const float* __restrict__ bias, u16* __restrict__ out,
              int IC, int IWp, int inSS,
              int OH, int OW, int OWp_o, int outSS, int pad_o,
              int Kpad, int relu, int n_mt, int n_pt)
{
    const int w    = blockIdx.x * 4 + (threadIdx.x >> 6);
    const int lane = threadIdx.x & 63;
    const int lr   = lane & 15, lg = lane >> 4;
    const int tilesPerB = n_mt * n_pt;
    const int b  = w / tilesPerB;
    const int r  = w - b * tilesPerB;
    const int mt = r / n_pt;
    const int pt = r - mt * n_pt;
    const int ocb = mt * 64;

    const int pe0 = pt * 32 + lr, pe1 = pe0 + 16;
    const int oh0 = pe0 / OW, ow0 = pe0 - oh0 * OW;
    const int oh1 = pe1 / OW, ow1 = pe1 - oh1 * OW;

    const u16* in0 = inP + (size_t)b * inSS + ((size_t)(oh0 * S) * IWp + ow0 * S) * IC;
    const u16* in1 = inP + (size_t)b * inSS + ((size_t)(oh1 * S) * IWp + ow1 * S) * IC;
    const u16* wrow[4];
    #pragma unroll
    for (int mf = 0; mf < 4; ++mf)
        wrow[mf] = Wp + (size_t)(ocb + mf * 16 + lr) * Kpad + lg * 8;

    f32x4 acc[4][2] = {};

    if ((IC & 31) == 0) {
        // IC multiple of 32: tap uniform across the wave per k-step
        for (int tap = 0; tap < 9; ++tap) {
            const int ky = (tap * 11) >> 5, kx = tap - 3 * ky;
            const u16* p0 = in0 + ((size_t)ky * IWp + kx) * IC + lg * 8;
            const u16* p1 = in1 + ((size_t)ky * IWp + kx) * IC + lg * 8;
            const int kb = tap * IC;
            for (int icb = 0; icb < IC; icb += 32) {
                const bf16x8 bv0 = ldb8(p0 + icb);
                const bf16x8 bv1 = ldb8(p1 + icb);
                #pragma unroll
                for (int mf = 0; mf < 4; ++mf) {
                    const bf16x8 av = ldb8(wrow[mf] + kb + icb);
                    acc[mf][0] = __builtin_amdgcn_mfma_f32_16x16x32_bf16(av, bv0, acc[mf][0], 0, 0, 0);
                    acc[mf][1] = __builtin_amdgcn_mfma_f32_16x16x32_bf16(av, bv1, acc[mf][1], 0, 0, 0);
                }
            }
        }
    } else {
        // IC == 16: one k-step spans 2 taps; per-lane tap/ic
        for (int kb = 0; kb < Kpad; kb += 32) {
            const int kt = kb + lg * 8;
            int tap = kt >> 4;
            if (tap > 8) tap = 8;                     // padded k, weight is 0
            const int ic = kt & 15;
            const int ky = (tap * 11) >> 5, kx = tap - 3 * ky;
            const size_t off = ((size_t)ky * IWp + kx) * 16 + ic;
            const bf16x8 bv0 = ldb8(in0 + off);
            const bf16x8 bv1 = ldb8(in1 + off);
            #pragma unroll
            for (int mf = 0; mf < 4; ++mf) {
                const bf16x8 av = ldb8(wrow[mf] + kb);
                acc[mf][0] = __builtin_amdgcn_mfma_f32_16x16x32_bf16(av, bv0, acc[mf][0], 0, 0, 0);
                acc[mf][1] = __builtin_amdgcn_mfma_f32_16x16x32_bf16(av, bv1, acc[mf][1], 0, 0, 0);
            }
        }
    }

    // epilogue: D col = lane&15 (pixel), row = lg*4 + reg (oc)
    #pragma unroll
    for (int mf = 0; mf < 4; ++mf) {
        const int oc0 = ocb + mf * 16 + lg * 4;
        const float* bp = bias + oc0;
        const float b0 = bp[0], b1 = bp[1], b2 = bp[2], b3 = bp[3];
        #pragma unroll
        for (int nf = 0; nf < 2; ++nf) {
            const int oh = nf ? oh1 : oh0, ow = nf ? ow1 : ow0;
            const f32x4 a = acc[mf][nf];
            float v0 = a[0] + b0, v1 = a[1] + b1, v2 = a[2] + b2, v3 = a[3] + b3;
            if (relu) {
                v0 = fmaxf(v0, 0.f); v1 = fmaxf(v1, 0.f);
                v2 = fmaxf(v2, 0.f); v3 = fmaxf(v3, 0.f);
            }
            u32x2 pk;
            pk[0] = (unsigned)f2bf(v0) | ((unsigned)f2bf(v1) << 16);
            pk[1] = (unsigned)f2bf(v2) | ((unsigned)f2bf(v3) << 16);
            u16* op = out + (size_t)b * outSS +
                 (((size_t)(oh + pad_o)) * OWp_o + (ow + pad_o)) * (size_t)(n_mt * 64) + oc0;
            *(u32x2*)op = pk;
        }
    }
}

// ---- xcorr as batched MFMA GEMM --------------------------------------------
// Per sample b: C[d][col] = dot_2048(cfm[b] + d*2048, ffm[b] + col_off),
// where col = y*25+ox, col_off = (y*32+ox)*256 (contiguous K!).
// Wave = 2 col-tiles of 16; A rows: d=0..7 valid, 8..15 zero.
__global__ __launch_bounds__(256)
void xcmf_k(const u16* __restrict__ ffm, const u16* __restrict__ cfm,
            float* __restrict__ R)
{
    const int w    = blockIdx.x * 4 + (threadIdx.x >> 6);   // 1600 waves
    const int lane = threadIdx.x & 63;
    const int lr   = lane & 15, lg = lane >> 4;
    const int b  = w / 25;
    const int tp = w - b * 25;

    const int col0 = tp * 32 + lr;          // tile 2*tp
    const int col1 = col0 + 16;             // tile 2*tp+1
    const int y0 = col0 / 25, x0 = col0 - y0 * 25;
    const int y1 = col1 / 25, x1 = col1 - y1 * 25;

    const u16* fb = ffm + (size_t)b * 262144;
    const u16* f0 = fb + ((size_t)y0 * 32 + x0) * 256 + lg * 8;
    const u16* f1 = fb + ((size_t)y1 * 32 + x1) * 256 + lg * 8;
    const u16* ab = cfm + (size_t)b * 16384 + (size_t)lr * 2048 + lg * 8;
    const bool arow = (lr < 8);

    f32x4 acc0 = {}, acc1 = {};
    #pragma unroll 4
    for (int kb = 0; kb < 2048; kb += 32) {
        const bf16x8 av = arow ? ldb8(ab + kb) : zerob8();
        const bf16x8 bv0 = ldb8(f0 + kb);
        const bf16x8 bv1 = ldb8(f1 + kb);
        acc0 = __builtin_amdgcn_mfma_f32_16x16x32_bf16(av, bv0, acc0, 0, 0, 0);
        acc1 = __builtin_amdgcn_mfma_f32_16x16x32_bf16(av, bv1, acc1, 0, 0, 0);
    }

    // D: col=lane&15 (our col tile), row=lg*4+j (d). Only d<8 valid.
    if (lg < 2) {
        float* rb = R + (size_t)b * 6400;
        #pragma unroll
        for (int j = 0; j < 4; ++j) {
            const int d = lg * 4 + j;
            rb[(size_t)d * 800 + col0] = acc0[j];
            rb[(size_t)d * 800 + col1] = acc1[j];
        }
    }
}

// ---- diagonal-band reduce: rmap[b][oy][ox] = sum_d R[b][d][(oy+d)*25+ox] ---
__global__ __launch_bounds__(256)
void xred_k(const float* __restrict__ R, float* __restrict__ part)
{
    const int i = blockIdx.x * 256 + threadIdx.x;
    if (i >= 40000) return;
    const int b = i / 625;
    const int o = i - b * 625;
    const float* rb = R + (size_t)b * 6400 + o;   // row 0: (oy)*25+ox
    float v = 0.f;
    #pragma unroll
    for (int d = 0; d < 8; ++d) v += rb[(size_t)d * 800 + d * 25];
    part[i] = v;
}

// ---- BatchNorm over all 40000 elements -------------------------------------
__global__ __launch_bounds__(1024)
void bn_k(const float* __restrict__ rmap, const float* __restrict__ gamma,
          const float* __restrict__ beta, float* __restrict__ out)
{
    const int N = 40000;
    const int tid = threadIdx.x;
    __shared__ float rs[1024], rq[1024];
    __shared__ float mean_s, inv_s;
    float s = 0.f, q = 0.f;
    for (int i = tid; i < N; i += 1024) {
        const float v = rmap[i];
        s += v; q += v * v;
    }
    rs[tid] = s; rq[tid] = q;
    __syncthreads();
    for (int off = 512; off > 0; off >>= 1) {
        if (tid < off) { rs[tid] += rs[tid + off]; rq[tid] += rq[tid + off]; }
        __syncthreads();
    }
    if (tid == 0) {
        const float m = rs[0] / (float)N;
        mean_s = m;
        inv_s = rsqrtf(rq[0] / (float)N - m * m + 1e-5f);
    }
    __syncthreads();
    const float g = gamma[0], bt = beta[0];
    for (int i = tid; i < N; i += 1024)
        out[i] = (rmap[i] - mean_s) * inv_s * g + bt;
}

// ---------------------------------------------------------------------------

extern "C" void kernel_launch(void* const* d_in, const int* in_sizes, int n_in,
                              void* d_out, int out_size, void* d_ws, size_t ws_size,
                              hipStream_t stream)
{
    (void)in_sizes; (void)n_in; (void)out_size; (void)ws_size;
    const float* crop  = (const float*)d_in[0];
    const float* frame = (const float*)d_in[1];
    const float* W[5]; const float* bb[5];
    for (int i = 0; i < 5; ++i) { W[i] = (const float*)d_in[2 + 2*i]; bb[i] = (const float*)d_in[3 + 2*i]; }
    const float* gamma = (const float*)d_in[12];
    const float* beta  = (const float*)d_in[13];
    float* out = (float*)d_out;

    unsigned char* ws = (unsigned char*)d_ws;
    // byte offsets (regions R1/R2 reused across pipeline stages)
    float* f0p   = (float*)(ws + 0);           // [64][130][130][3] f32  (dead after fL1)
    u16*   f1p   = (u16*)(ws + 12979200);      // [64][66][66][16] bf16  (dead after fL2)
    u16*   f3p   = (u16*)(ws + 0);             // [64][34][34][128] bf16 (aliases f0p+f1p)
    u16*   f2p   = (u16*)(ws + 21900288);      // [64][66][66][64] bf16  (dead after fL3)
    u16*   ffm   = (u16*)(ws + 21900288);      // [64][32][32][256] bf16 (aliases f2p)
    float* c0p   = (float*)(ws + 57584640);    // [64][34][34][3] f32
    u16*   c1p   = (u16*)(ws + 58472448);      // [64][18][18][16]
    u16*   c2p   = (u16*)(ws + 59136000);      // [64][18][18][64]
    u16*   c3p   = (u16*)(ws + 61790208);      // [64][10][10][128]
    u16*   cfm   = (u16*)(ws + 63428608);      // [64][8][8][256]
    u16*   Wp2   = (u16*)(ws + 65525760);      // [64][160]
    u16*   Wp3   = (u16*)(ws + 65546240);      // [128][576]
    u16*   Wp4   = (u16*)(ws + 65693696);      // [256][1152]
    float* part  = (float*)(ws + 66283520);    // [40000]
    float* Rbuf  = (float*)(ws + 66443520);    // [64][8][800] f32 = 1.6 MB

    // zero halos (and scratch) — must be per-call (ws poisoned before timing)
    hipMemsetAsync(ws + 0,        0, 21900288, stream);   // f0p+f1p
    hipMemsetAsync(ws + 21900288, 0, 35684352, stream);   // f2p
    hipMemsetAsync(ws + 57584640, 0, 5843968,  stream);   // c0p..c3p

    // pack weights to bf16 [oc][Kpad]
    packw_k<<<40,   256, 0, stream>>>(W[2], Wp2,  64,  16,  160);
    packw_k<<<288,  256, 0, stream>>>(W[3], Wp3, 128,  64,  576);
    packw_k<<<1152, 256, 0, stream>>>(W[4], Wp4, 256, 128, 1152);

    // ---- crop encoder ----
    conv0_k<<<256, 256, 0, stream>>>(crop, W[0], bb[0], c0p, 64, 64, 64, 32, 32);
    conv1_k<<<64,  256, 0, stream>>>(c0p, W[1], bb[1], c1p, 64, 34, 34, 16, 16);
    convmf_k<1><<<128, 256, 0, stream>>>(c1p, Wp2, bb[2], c2p,  16, 18,  5184, 16, 16, 18, 20736, 1,  160, 1, 1, 8);
    convmf_k<2><<<64,  256, 0, stream>>>(c2p, Wp3, bb[3], c3p,  64, 18, 20736,  8,  8, 10, 12800, 1,  576, 1, 2, 2);
    convmf_k<1><<<128, 256, 0, stream>>>(c3p, Wp4, bb[4], cfm, 128, 10, 12800,  8,  8,  8, 16384, 0, 1152, 0, 4, 2);

    // ---- frame encoder ----
    conv0_k<<<4096, 256, 0, stream>>>(frame, W[0], bb[0], f0p, 64, 256, 256, 128, 128);
    conv1_k<<<1024, 256, 0, stream>>>(f0p, W[1], bb[1], f1p, 64, 130, 130, 64, 64);
    convmf_k<1><<<2048, 256, 0, stream>>>(f1p, Wp2, bb[2], f2p,  16, 66,  69696, 64, 64, 66, 278784, 1,  160, 1, 1, 128);
    hipMemsetAsync(ws + 0, 0, 18939904, stream);          // f3p halo (f0p/f1p dead)
    convmf_k<2><<<1024, 256, 0, stream>>>(f2p, Wp3, bb[3], f3p,  64, 66, 278784, 32, 32, 34, 147968, 1,  576, 1, 2, 32);
    convmf_k<1><<<2048, 256, 0, stream>>>(f3p, Wp4, bb[4], ffm, 128, 34, 147968, 32, 32, 32, 262144, 0, 1152, 0, 4, 32);

    // ---- xcorr (MFMA) + band-reduce + BN ----
    xcmf_k<<<400, 256, 0, stream>>>(ffm, cfm, Rbuf);
    xred_k<<<157, 256, 0, stream>>>(Rbuf, part);
    bn_k<<<1, 1024, 0, stream>>>(part, gamma, beta, out);
}

// Round 4
// 355.284 us; speedup vs baseline: 38.9849x; 1.4749x over previous
//
#include <hip/hip_runtime.h>

// ---------------------------------------------------------------------------
// CorrelationalDetector R4: conv layers 2-4 as tiled MFMA GEMM with
// double-buffered LDS staging via global_load_lds (im2col folded into the
// per-lane global source address; LDS dest linear). BK=32, fragment-order
// LDS layout [k/8][row][8elem] -> conflict-free ds_read_b128.
// ---------------------------------------------------------------------------

typedef __bf16 bf16x8 __attribute__((ext_vector_type(8)));
typedef float f32x4 __attribute__((ext_vector_type(4)));
typedef unsigned int u32x4 __attribute__((ext_vector_type(4)));
typedef unsigned int u32x2 __attribute__((ext_vector_type(2)));
typedef unsigned short u16;

#define AS1 __attribute__((address_space(1)))
#define AS3 __attribute__((address_space(3)))

__device__ __forceinline__ u16 f2bf(float v) {
    unsigned u = __float_as_uint(v);
    u += 0x7fffu + ((u >> 16) & 1u);          // RNE
    return (u16)(u >> 16);
}

__device__ __forceinline__ bf16x8 ldb8(const u16* p) {
    return *(const bf16x8*)p;
}

__device__ __forceinline__ bf16x8 zerob8() {
    u32x4 z = {0u, 0u, 0u, 0u};
    bf16x8 r;
    __builtin_memcpy(&r, &z, 16);
    return r;
}

__device__ __forceinline__ void gload16(const u16* g, u16* l) {
    __builtin_amdgcn_global_load_lds((const AS1 void*)g, (AS3 void*)l, 16, 0, 0);
}

// ---- zero the 1-px halo border of an NHWC-padded buffer --------------------
__global__ __launch_bounds__(256)
void haloz_k(float* __restrict__ base, int B, int Hp, int Wpx, int wpp)
{
    const int bord = 2 * Wpx + 2 * (Hp - 2);
    const int sampW = Hp * Wpx * wpp;
    const int total = B * bord * wpp;
    for (int i = blockIdx.x * 256 + threadIdx.x; i < total; i += gridDim.x * 256) {
        const int w = i % wpp; int t2 = i / wpp;
        const int pb = t2 % bord; const int b = t2 / bord;
        int oh, ow;
        if (pb < Wpx)            { oh = 0;      ow = pb; }
        else if (pb < 2 * Wpx)   { oh = Hp - 1; ow = pb - Wpx; }
        else { const int q = pb - 2 * Wpx; oh = 1 + (q >> 1); ow = (q & 1) ? (Wpx - 1) : 0; }
        base[(size_t)b * sampW + ((size_t)oh * Wpx + ow) * wpp + w] = 0.f;
    }
}

// ---- L0: IC=3,OC=3, stride2, NCHW fp32 in -> NHWC fp32 padded out ----------
__global__ __launch_bounds__(256)
void conv0_k(const float* __restrict__ in, const float* __restrict__ W,
             const float* __restrict__ bias, float* __restrict__ outP,
             int Btot, int IH, int IW, int OH, int OW)
{
    const int OWp = OW + 2, OHp = OH + 2;
    const int total = Btot * OH * OW;
    for (int idx = blockIdx.x * blockDim.x + threadIdx.x; idx < total;
         idx += gridDim.x * blockDim.x) {
        const int ow = idx % OW; int t = idx / OW;
        const int oh = t % OH;  const int b = t / OH;
        float a0 = bias[0], a1 = bias[1], a2 = bias[2];
        const float* inb = in + (size_t)b * 3 * IH * IW;
        for (int ic = 0; ic < 3; ++ic) {
            const float* ip = inb + (size_t)ic * IH * IW;
            #pragma unroll
            for (int ky = 0; ky < 3; ++ky) {
                const int y = oh * 2 - 1 + ky;
                if ((unsigned)y >= (unsigned)IH) continue;
                #pragma unroll
                for (int kx = 0; kx < 3; ++kx) {
                    const int x = ow * 2 - 1 + kx;
                    if ((unsigned)x >= (unsigned)IW) continue;
                    const float v = ip[(size_t)y * IW + x];
                    const int wi = ic * 9 + ky * 3 + kx;
                    a0 += v * W[wi]; a1 += v * W[27 + wi]; a2 += v * W[54 + wi];
                }
            }
        }
        float* op = outP + (((size_t)b * OHp + oh + 1) * OWp + ow + 1) * 3;
        op[0] = fmaxf(a0, 0.f); op[1] = fmaxf(a1, 0.f); op[2] = fmaxf(a2, 0.f);
    }
}

// ---- L1: IC=3,OC=16, stride2, NHWC fp32 padded in -> NHWC bf16 padded out --
__global__ __launch_bounds__(256)
void conv1_k(const float* __restrict__ inP, const float* __restrict__ W,
             const float* __restrict__ bias, u16* __restrict__ outP,
             int Btot, int IHp, int IWp, int OH, int OW)
{
    const int OWp = OW + 2, OHp = OH + 2;
    const int total = Btot * OH * OW;
    for (int idx = blockIdx.x * blockDim.x + threadIdx.x; idx < total;
         idx += gridDim.x * blockDim.x) {
        const int ow = idx % OW; int t = idx / OW;
        const int oh = t % OH;  const int b = t / OH;
        float acc[16];
        #pragma unroll
        for (int oc = 0; oc < 16; ++oc) acc[oc] = bias[oc];
        const float* ib = inP + (size_t)b * IHp * IWp * 3;
        #pragma unroll
        for (int ky = 0; ky < 3; ++ky) {
            #pragma unroll
            for (int kx = 0; kx < 3; ++kx) {
                const float* p = ib + (((size_t)(oh * 2 + ky)) * IWp + (ow * 2 + kx)) * 3;
                const float x0 = p[0], x1 = p[1], x2 = p[2];
                const float* wp = W + ky * 3 + kx;       // W[oc*27 + ic*9 + tap]
                #pragma unroll
                for (int oc = 0; oc < 16; ++oc)
                    acc[oc] += x0 * wp[oc * 27] + x1 * wp[oc * 27 + 9] + x2 * wp[oc * 27 + 18];
            }
        }
        u16* op = outP + (((size_t)b * OHp + oh + 1) * OWp + ow + 1) * 16;
        #pragma unroll
        for (int oc = 0; oc < 16; ++oc) op[oc] = f2bf(fmaxf(acc[oc], 0.f));
    }
}

// ---- weight pack: OIHW fp32 -> [oc][Kpad] bf16, k = tap*IC + ic ------------
__global__ __launch_bounds__(256)
void packw_k(const float* __restrict__ W, u16* __restrict__ Wp,
             int OC, int IC, int Kpad)
{
    const int total = OC * Kpad;
    for (int idx = blockIdx.x * blockDim.x + threadIdx.x; idx < total;
         idx += gridDim.x * blockDim.x) {
        const int k = idx % Kpad, oc = idx / Kpad;
        const int tap = k / IC, ic = k % IC;
        const float v = (tap < 9) ? W[((size_t)oc * IC + ic) * 9 + tap] : 0.f;
        Wp[idx] = f2bf(v);
    }
}

// ---- tiled MFMA implicit-GEMM conv3x3 (pad=1), LDS double-buffered ---------
// Block: 256 threads = 4 waves (NWM x NWN).  Tile BM oc x BN px, BK=32.
// LDS fragment order: slot = (k/8)*ROWS + row, 16B per slot.
template<int BM, int BN, int NWM, int NWN, int S>
__global__ __launch_bounds__(256)
void convg_k(const u16* __restrict__ inP, const u16* __restrict__ Wp,
             const float* __restrict__ bias, u16* __restrict__ out,
             int IC_sh, int IWp, int inSS, int OW_sh, int OWp_o, int outSS,
             int pad_o, int Kreal, int nt, int Kpad, int relu, int n_pt, int OCtot)
{
    constexpr int MF = BM / (NWM * 16);
    constexpr int NF = BN / (NWN * 16);
    constexpr int ASLOT = BM * 4;               // 16B slots per A buffer
    constexpr int BSLOT = BN * 4;
    constexpr int AISS = ASLOT / 256;
    constexpr int BISS = BSLOT / 256;

    __shared__ __align__(16) u16 Ab[2][ASLOT * 8];
    __shared__ __align__(16) u16 Bb[2][BSLOT * 8];

    const int t    = threadIdx.x;
    const int wv   = t >> 6, lane = t & 63;
    const int lr   = lane & 15, lg = lane >> 4;
    const int wm   = wv / NWN, wn = wv % NWN;

    const int tilesPerB = (OCtot / BM) * n_pt;
    const int b  = blockIdx.x / tilesPerB;
    const int r0 = blockIdx.x - b * tilesPerB;
    const int mt = r0 / n_pt, pt = r0 - mt * n_pt;
    const int ocb = mt * BM, pxb = pt * BN;
    const int IC = 1 << IC_sh;
    const int OW = 1 << OW_sh;

    const u16* __restrict__ inb = inP + (size_t)b * inSS;

    // per-thread staging geometry (constant over the K loop)
    const u16* agp[AISS];
    #pragma unroll
    for (int i = 0; i < AISS; ++i) {
        const int s = i * 256 + t;
        const int q = s / BM, rr = s - q * BM;
        agp[i] = Wp + (size_t)(ocb + rr) * Kpad + q * 8;
    }
    int bq[BISS]; const u16* bpx[BISS];
    #pragma unroll
    for (int i = 0; i < BISS; ++i) {
        const int s = i * 256 + t;
        const int q = s / BN, rr = s - q * BN;
        const int px = pxb + rr;
        const int oh = px >> OW_sh, ow = px & (OW - 1);
        bq[i] = q;
        bpx[i] = inb + ((size_t)(oh * S) * IWp + ow * S) * IC;
    }

    f32x4 acc[MF][NF] = {};

    auto STAGE = [&](int buf, int kb) {
        #pragma unroll
        for (int i = 0; i < AISS; ++i)
            gload16(agp[i] + kb, &Ab[buf][(size_t)(i * 256 + wv * 64) * 8]);
        #pragma unroll
        for (int i = 0; i < BISS; ++i) {
            const int k = kb + bq[i] * 8;
            const int tap = k >> IC_sh;
            const int ic = k & (IC - 1);
            const int ky = (tap * 11) >> 5, kx = tap - 3 * ky;
            const u16* g = bpx[i] + ((size_t)ky * IWp + kx) * IC + ic;
            if (k >= Kreal) g = inb;           // halo corner = zeros
            gload16(g, &Bb[buf][(size_t)(i * 256 + wv * 64) * 8]);
        }
    };

    int cur = 0;
    STAGE(0, 0);
    __syncthreads();

    for (int ks = 0; ks < nt; ++ks) {
        if (ks + 1 < nt) STAGE(cur ^ 1, (ks + 1) * 32);
        bf16x8 af[MF], bf_[NF];
        #pragma unroll
        for (int m = 0; m < MF; ++m)
            af[m] = ldb8(&Ab[cur][(size_t)(lg * BM + wm * (MF * 16) + m * 16 + lr) * 8]);
        #pragma unroll
        for (int n = 0; n < NF; ++n)
            bf_[n] = ldb8(&Bb[cur][(size_t)(lg * BN + wn * (NF * 16) + n * 16 + lr) * 8]);
        #pragma unroll
        for (int m = 0; m < MF; ++m)
            #pragma unroll
            for (int n = 0; n < NF; ++n)
                acc[m][n] = __builtin_amdgcn_mfma_f32_16x16x32_bf16(af[m], bf_[n], acc[m][n], 0, 0, 0);
        __syncthreads();
        cur ^= 1;
    }

    // epilogue: D col = lr (pixel), row = lg*4+j (oc)
    #pragma unroll
    for (int m = 0; m < MF; ++m) {
        const int oc0 = ocb + wm * (MF * 16) + m * 16 + lg * 4;
        const float b0 = bias[oc0], b1 = bias[oc0 + 1], b2 = bias[oc0 + 2], b3 = bias[oc0 + 3];
        #pragma unroll
        for (int n = 0; n < NF; ++n) {
            const int px = pxb + wn * (NF * 16) + n * 16 + lr;
            const int oh = px >> OW_sh, ow = px & (OW - 1);
            const f32x4 a = acc[m][n];
            float v0 = a[0] + b0, v1 = a[1] + b1, v2 = a[2] + b2, v3 = a[3] + b3;
            if (relu) {
                v0 = fmaxf(v0, 0.f); v1 = fmaxf(v1, 0.f);
                v2 = fmaxf(v2, 0.f); v3 = fmaxf(v3, 0.f);
            }
            u32x2 pk;
            pk[0] = (unsigned)f2bf(v0) | ((unsigned)f2bf(v1) << 16);
            pk[1] = (unsigned)f2bf(v2) | ((unsigned)f2bf(v3) << 16);
            u16* op = out + (size_t)b * outSS +
                      (((size_t)(oh + pad_o)) * OWp_o + (ow + pad_o)) * (size_t)OCtot + oc0;
            *(u32x2*)op = pk;
        }
    }
}

// ---- xcorr as batched MFMA GEMM --------------------------------------------
__global__ __launch_bounds__(256)
void xcmf_k(const u16* __restrict__ ffm, const u16* __restrict__ cfm,
            float* __restrict__ R)
{
    const int w    = blockIdx.x * 4 + (threadIdx.x >> 6);   // 1600 waves
    const int lane = threadIdx.x & 63;
    const int lr   = lane & 15, lg = lane >> 4;
    const int b  = w / 25;
    const int tp = w - b * 25;

    const int col0 = tp * 32 + lr;
    const int col1 = col0 + 16;
    const int y0 = col0 / 25, x0 = col0 - y0 * 25;
    const int y1 = col1 / 25, x1 = col1 - y1 * 25;

    const u16* fb = ffm + (size_t)b * 262144;
    const u16* f0 = fb + ((size_t)y0 * 32 + x0) * 256 + lg * 8;
    const u16* f1 = fb + ((size_t)y1 * 32 + x1) * 256 + lg * 8;
    const u16* ab = cfm + (size_t)b * 16384 + (size_t)lr * 2048 + lg * 8;
    const bool arow = (lr < 8);

    f32x4 acc0 = {}, acc1 = {};
    #pragma unroll 4
    for (int kb = 0; kb < 2048; kb += 32) {
        const bf16x8 av = arow ? ldb8(ab + kb) : zerob8();
        const bf16x8 bv0 = ldb8(f0 + kb);
        const bf16x8 bv1 = ldb8(f1 + kb);
        acc0 = __builtin_amdgcn_mfma_f32_16x16x32_bf16(av, bv0, acc0, 0, 0, 0);
        acc1 = __builtin_amdgcn_mfma_f32_16x16x32_bf16(av, bv1, acc1, 0, 0, 0);
    }

    if (lg < 2) {
        float* rb = R + (size_t)b * 6400;
        #pragma unroll
        for (int j = 0; j < 4; ++j) {
            const int d = lg * 4 + j;
            rb[(size_t)d * 800 + col0] = acc0[j];
            rb[(size_t)d * 800 + col1] = acc1[j];
        }
    }
}

// ---- diagonal-band reduce --------------------------------------------------
__global__ __launch_bounds__(256)
void xred_k(const float* __restrict__ R, float* __restrict__ part)
{
    const int i = blockIdx.x * 256 + threadIdx.x;
    if (i >= 40000) return;
    const int b = i / 625;
    const int o = i - b * 625;
    const float* rb = R + (size_t)b * 6400 + o;
    float v = 0.f;
    #pragma unroll
    for (int d = 0; d < 8; ++d) v += rb[(size_t)d * 800 + d * 25];
    part[i] = v;
}

// ---- BatchNorm over all 40000 elements -------------------------------------
__global__ __launch_bounds__(1024)
void bn_k(const float* __restrict__ rmap, const float* __restrict__ gamma,
          const float* __restrict__ beta, float* __restrict__ out)
{
    const int N = 40000;
    const int tid = threadIdx.x;
    __shared__ float rs[1024], rq[1024];
    __shared__ float mean_s, inv_s;
    float s = 0.f, q = 0.f;
    for (int i = tid; i < N; i += 1024) {
        const float v = rmap[i];
        s += v; q += v * v;
    }
    rs[tid] = s; rq[tid] = q;
    __syncthreads();
    for (int off = 512; off > 0; off >>= 1) {
        if (tid < off) { rs[tid] += rs[tid + off]; rq[tid] += rq[tid + off]; }
        __syncthreads();
    }
    if (tid == 0) {
        const float m = rs[0] / (float)N;
        mean_s = m;
        inv_s = rsqrtf(rq[0] / (float)N - m * m + 1e-5f);
    }
    __syncthreads();
    const float g = gamma[0], bt = beta[0];
    for (int i = tid; i < N; i += 1024)
        out[i] = (rmap[i] - mean_s) * inv_s * g + bt;
}

// ---------------------------------------------------------------------------

extern "C" void kernel_launch(void* const* d_in, const int* in_sizes, int n_in,
                              void* d_out, int out_size, void* d_ws, size_t ws_size,
                              hipStream_t stream)
{
    (void)in_sizes; (void)n_in; (void)out_size; (void)ws_size;
    const float* crop  = (const float*)d_in[0];
    const float* frame = (const float*)d_in[1];
    const float* W[5]; const float* bb[5];
    for (int i = 0; i < 5; ++i) { W[i] = (const float*)d_in[2 + 2*i]; bb[i] = (const float*)d_in[3 + 2*i]; }
    const float* gamma = (const float*)d_in[12];
    const float* beta  = (const float*)d_in[13];
    float* out = (float*)d_out;

    unsigned char* ws = (unsigned char*)d_ws;
    float* f0p   = (float*)(ws + 0);           // [64][130][130][3] f32  (dead after fL1)
    u16*   f1p   = (u16*)(ws + 12979200);      // [64][66][66][16] bf16  (dead after fL2)
    u16*   f3p   = (u16*)(ws + 0);             // [64][34][34][128] bf16 (aliases f0p+f1p)
    u16*   f2p   = (u16*)(ws + 21900288);      // [64][66][66][64] bf16
    u16*   ffm   = (u16*)(ws + 21900288);      // [64][32][32][256] bf16 (aliases f2p)
    float* c0p   = (float*)(ws + 57584640);    // [64][34][34][3] f32
    u16*   c1p   = (u16*)(ws + 58472448);      // [64][18][18][16]
    u16*   c2p   = (u16*)(ws + 59136000);      // [64][18][18][64]
    u16*   c3p   = (u16*)(ws + 61790208);      // [64][10][10][128]
    u16*   cfm   = (u16*)(ws + 63428608);      // [64][8][8][256]
    u16*   Wp2   = (u16*)(ws + 65525760);      // [64][160]
    u16*   Wp3   = (u16*)(ws + 65546240);      // [128][576]
    u16*   Wp4   = (u16*)(ws + 65693696);      // [256][1152]
    float* part  = (float*)(ws + 66283520);    // [40000]
    float* Rbuf  = (float*)(ws + 66443520);    // [64][8][800] f32

    // halo zeroing (replaces bulk memsets); interiors fully written by convs
    haloz_k<<<99,   256, 0, stream>>>(c0p,          64,  34,  34,  3);
    haloz_k<<<136,  256, 0, stream>>>((float*)c1p,  64,  18,  18,  8);
    haloz_k<<<544,  256, 0, stream>>>((float*)c2p,  64,  18,  18, 32);
    haloz_k<<<576,  256, 0, stream>>>((float*)c3p,  64,  10,  10, 64);
    haloz_k<<<387,  256, 0, stream>>>(f0p,          64, 130, 130,  3);
    haloz_k<<<1024, 256, 0, stream>>>((float*)f1p,  64,  66,  66,  8);
    haloz_k<<<1024, 256, 0, stream>>>((float*)f2p,  64,  66,  66, 32);

    // pack weights to bf16 [oc][Kpad]
    packw_k<<<40,   256, 0, stream>>>(W[2], Wp2,  64,  16,  160);
    packw_k<<<288,  256, 0, stream>>>(W[3], Wp3, 128,  64,  576);
    packw_k<<<1152, 256, 0, stream>>>(W[4], Wp4, 256, 128, 1152);

    // ---- crop encoder: 64x64 ->32 ->16 ->16 ->8 ->8 ----
    conv0_k<<<256, 256, 0, stream>>>(crop, W[0], bb[0], c0p, 64, 64, 64, 32, 32);
    conv1_k<<<64,  256, 0, stream>>>(c0p, W[1], bb[1], c1p, 64, 34, 34, 16, 16);
    //                 inP  Wp   bias  out  ICsh IWp inSS  OWsh OWpo outSS pad Kreal nt Kpad relu npt OCtot
    convg_k< 64,256,1,4,1><<< 64, 256, 0, stream>>>(c1p, Wp2, bb[2], c2p, 4, 18,  5184, 4, 18, 20736, 1, 144,  5,  160, 1, 1,  64);
    convg_k<128, 64,4,1,2><<< 64, 256, 0, stream>>>(c2p, Wp3, bb[3], c3p, 6, 18, 20736, 3, 10, 12800, 1, 576, 18,  576, 1, 1, 128);
    convg_k<256, 64,4,1,1><<< 64, 256, 0, stream>>>(c3p, Wp4, bb[4], cfm, 7, 10, 12800, 3,  8, 16384, 0, 1152, 36, 1152, 0, 1, 256);

    // ---- frame encoder: 256x256 ->128 ->64 ->64 ->32 ->32 ----
    conv0_k<<<4096, 256, 0, stream>>>(frame, W[0], bb[0], f0p, 64, 256, 256, 128, 128);
    conv1_k<<<1024, 256, 0, stream>>>(f0p, W[1], bb[1], f1p, 64, 130, 130, 64, 64);
    convg_k< 64,256,1,4,1><<<1024, 256, 0, stream>>>(f1p, Wp2, bb[2], f2p, 4, 66,  69696, 6, 66, 278784, 1, 144,  5,  160, 1, 16,  64);
    haloz_k<<<1024, 256, 0, stream>>>((float*)f3p, 64, 34, 34, 64);   // f0p/f1p dead now
    convg_k<128,128,2,2,2><<< 512, 256, 0, stream>>>(f2p, Wp3, bb[3], f3p, 6, 66, 278784, 5, 34, 147968, 1, 576, 18,  576, 1, 8, 128);
    convg_k<128,128,2,2,1><<<1024, 256, 0, stream>>>(f3p, Wp4, bb[4], ffm, 7, 34, 147968, 5, 32, 262144, 0, 1152, 36, 1152, 0, 8, 256);

    // ---- xcorr (MFMA) + band-reduce + BN ----
    xcmf_k<<<400, 256, 0, stream>>>(ffm, cfm, Rbuf);
    xred_k<<<157, 256, 0, stream>>>(Rbuf, part);
    bn_k<<<1, 1024, 0, stream>>>(part, gamma, beta, out);
}

// Round 6
// 321.226 us; speedup vs baseline: 43.1184x; 1.1060x over previous
//
#include <hip/hip_runtime.h>

// ---------------------------------------------------------------------------
// CorrelationalDetector R6 (= R5 with two fixes):
//  FIX 1: workspace map — f3p is 18,939,904 BYTES (R5 wrote 9,469,952 =
//         element count -> ffm overlapped f3p's second half, absmax 6.0).
//         ffm now aliases dead f0b+f1p+f2p; crop/weights after f3p. 82.4 MB.
//  FIX 2: raw s_barrier now fenced with asm("" ::: "memory") both sides so
//         ds_reads can't hoist between wait_vm and the barrier.
//  Carried from R5: convg2 counted-vmcnt pipeline, conv1 as MFMA GEMM,
//  merged halo-zero + weight-pack launches.
// ---------------------------------------------------------------------------

typedef __bf16 bf16x8 __attribute__((ext_vector_type(8)));
typedef float f32x4 __attribute__((ext_vector_type(4)));
typedef unsigned int u32x4 __attribute__((ext_vector_type(4)));
typedef unsigned int u32x2 __attribute__((ext_vector_type(2)));
typedef unsigned short u16;

#define AS1 __attribute__((address_space(1)))
#define AS3 __attribute__((address_space(3)))

__device__ __forceinline__ u16 f2bf(float v) {
    unsigned u = __float_as_uint(v);
    u += 0x7fffu + ((u >> 16) & 1u);          // RNE
    return (u16)(u >> 16);
}

__device__ __forceinline__ bf16x8 ldb8(const u16* p) {
    return *(const bf16x8*)p;
}

__device__ __forceinline__ bf16x8 zerob8() {
    u32x4 z = {0u, 0u, 0u, 0u};
    bf16x8 r;
    __builtin_memcpy(&r, &z, 16);
    return r;
}

__device__ __forceinline__ void gload16(const u16* g, u16* l) {
    __builtin_amdgcn_global_load_lds((const AS1 void*)g, (AS3 void*)l, 16, 0, 0);
}

template<int N> __device__ __forceinline__ void wait_vm() {
    if constexpr (N == 0)      asm volatile("s_waitcnt vmcnt(0)" ::: "memory");
    else if constexpr (N == 3) asm volatile("s_waitcnt vmcnt(3)" ::: "memory");
    else if constexpr (N == 4) asm volatile("s_waitcnt vmcnt(4)" ::: "memory");
    else if constexpr (N == 5) asm volatile("s_waitcnt vmcnt(5)" ::: "memory");
    else static_assert(N == 0, "unsupported vmcnt");
}

// barrier with compiler memory fences on both sides (no extra instructions)
__device__ __forceinline__ void bar_mem() {
    asm volatile("" ::: "memory");
    __builtin_amdgcn_s_barrier();
    asm volatile("" ::: "memory");
}

// ---- merged halo zero ------------------------------------------------------
struct HZd { unsigned long long ptr; int B, Hp, Wpx, w8, cum; };
struct HZall { HZd d[8]; int total; };

__global__ __launch_bounds__(256)
void haloz_k(HZall h)
{
    for (int i = blockIdx.x * 256 + threadIdx.x; i < h.total; i += gridDim.x * 256) {
        int di = 0;
        #pragma unroll
        for (int j = 1; j < 8; ++j) if (i >= h.d[j].cum) di = j;
        const HZd D = h.d[di];
        const int loc = i - D.cum;
        const int w = loc % D.w8; int t2 = loc / D.w8;
        const int bord = 2 * D.Wpx + 2 * (D.Hp - 2);
        const int pb = t2 % bord; const int b = t2 / bord;
        int oh, ow;
        if (pb < D.Wpx)            { oh = 0;        ow = pb; }
        else if (pb < 2 * D.Wpx)   { oh = D.Hp - 1; ow = pb - D.Wpx; }
        else { const int q = pb - 2 * D.Wpx; oh = 1 + (q >> 1); ow = (q & 1) ? (D.Wpx - 1) : 0; }
        ((unsigned long long*)D.ptr)[((size_t)b * D.Hp * D.Wpx + (size_t)oh * D.Wpx + ow) * D.w8 + w] = 0ull;
    }
}

// ---- merged weight pack ----------------------------------------------------
__device__ __forceinline__ void packone(const float* W, u16* Wp, int idx,
                                        int ICsh, int Kpad)
{
    const int k = idx % Kpad, oc = idx / Kpad;
    const int tap = k >> ICsh, ic = k & ((1 << ICsh) - 1);
    const float v = (tap < 9) ? W[((size_t)(oc << ICsh) + ic) * 9 + tap] : 0.f;
    Wp[idx] = f2bf(v);
}

__global__ __launch_bounds__(256)
void packall_k(const float* __restrict__ W1, const float* __restrict__ W2,
               const float* __restrict__ W3, const float* __restrict__ W4,
               u16* __restrict__ Wc1, u16* __restrict__ Wp2,
               u16* __restrict__ Wp3, u16* __restrict__ Wp4)
{
    const int i = blockIdx.x * 256 + threadIdx.x;
    if (i < 1024) {                       // Wc1: [16][64], k = ky*16+kx*4+ic
        const int k = i & 63, oc = i >> 6;
        const int ky = k >> 4, kx = (k >> 2) & 3, ic = k & 3;
        const float v = (ky < 3 && kx < 3 && ic < 3) ? W1[oc * 27 + ic * 9 + ky * 3 + kx] : 0.f;
        Wc1[i] = f2bf(v);
    } else if (i < 11264) {               // 1024 + 64*160
        packone(W2, Wp2, i - 1024, 4, 160);
    } else if (i < 84992) {               // + 128*576
        packone(W3, Wp3, i - 11264, 6, 576);
    } else if (i < 379904) {              // + 256*1152
        packone(W4, Wp4, i - 84992, 7, 1152);
    }
}

// ---- L0: IC=3,OC=3, stride2, NCHW fp32 in -> NHWC bf16 4ch padded out ------
__global__ __launch_bounds__(256)
void conv0_k(const float* __restrict__ in, const float* __restrict__ W,
             const float* __restrict__ bias, u16* __restrict__ outP,
             int Btot, int IH, int IW, int OH, int OW)
{
    const int OW4 = OW >> 2;
    const int OWp = OW + 2, OHp = OH + 2;
    const int total = Btot * OH * OW4;
    for (int idx = blockIdx.x * 256 + threadIdx.x; idx < total; idx += gridDim.x * 256) {
        const int ow4 = idx % OW4; int t = idx / OW4;
        const int oh = t % OH;  const int b = t / OH;
        const int owb = ow4 * 4;
        float a0[4], a1[4], a2[4];
        #pragma unroll
        for (int j = 0; j < 4; ++j) { a0[j] = bias[0]; a1[j] = bias[1]; a2[j] = bias[2]; }
        const float* inb = in + (size_t)b * 3 * IH * IW;
        const int xbase = owb * 2 - 1;
        #pragma unroll
        for (int ic = 0; ic < 3; ++ic) {
            const float* ip = inb + (size_t)ic * IH * IW;
            #pragma unroll
            for (int ky = 0; ky < 3; ++ky) {
                const int y = oh * 2 - 1 + ky;
                if ((unsigned)y >= (unsigned)IH) continue;
                const float* rp = ip + (size_t)y * IW;
                float xr[9];
                #pragma unroll
                for (int i2 = 0; i2 < 9; ++i2) {
                    const int x = xbase + i2;
                    xr[i2] = ((unsigned)x < (unsigned)IW) ? rp[x] : 0.f;
                }
                #pragma unroll
                for (int kx = 0; kx < 3; ++kx) {
                    const float w0 = W[0 * 27 + ic * 9 + ky * 3 + kx];
                    const float w1 = W[1 * 27 + ic * 9 + ky * 3 + kx];
                    const float w2 = W[2 * 27 + ic * 9 + ky * 3 + kx];
                    #pragma unroll
                    for (int j = 0; j < 4; ++j) {
                        const float xv = xr[2 * j + kx];
                        a0[j] += xv * w0; a1[j] += xv * w1; a2[j] += xv * w2;
                    }
                }
            }
        }
        u16* op = outP + (((size_t)b * OHp + oh + 1) * OWp + owb + 1) * 4;
        #pragma unroll
        for (int j = 0; j < 4; ++j) {
            u32x2 pk;
            pk[0] = (unsigned)f2bf(fmaxf(a0[j], 0.f)) | ((unsigned)f2bf(fmaxf(a1[j], 0.f)) << 16);
            pk[1] = (unsigned)f2bf(fmaxf(a2[j], 0.f));
            *(u32x2*)(op + j * 4) = pk;
        }
    }
}

// ---- L1 as MFMA GEMM: M=16 oc, K=64 (ky*16+kx*4+ic), N = all px ------------
template<int OWsh, int HWsh>
__global__ __launch_bounds__(256)
void conv1g_k(const u16* __restrict__ inP, const u16* __restrict__ Wc1,
              const float* __restrict__ bias, u16* __restrict__ outP,
              int IWp, int inSS, int OWp, int outSS)
{
    const int w = blockIdx.x * 4 + (threadIdx.x >> 6);
    const int lane = threadIdx.x & 63, lr = lane & 15, lg = lane >> 4;
    const int pxb = w * 64;
    const int OW = 1 << OWsh;

    const bf16x8 av0 = ldb8(Wc1 + lr * 64 + lg * 8);
    const bf16x8 av1 = ldb8(Wc1 + lr * 64 + 32 + lg * 8);
    const int ky0 = lg >> 1,     kxb = (lg & 1) * 2;
    const int ky1 = 2 + (lg >> 1);

    f32x4 acc[4] = {};
    #pragma unroll
    for (int n = 0; n < 4; ++n) {
        const int px = pxb + n * 16 + lr;
        const int b = px >> HWsh;
        const int rem = px & ((1 << HWsh) - 1);
        const int oh = rem >> OWsh, ow = rem & (OW - 1);
        const u16* ib = inP + (size_t)b * inSS + (((size_t)(oh * 2)) * IWp + ow * 2) * 4;
        const bf16x8 bv0 = ldb8(ib + ((size_t)ky0 * IWp + kxb) * 4);
        acc[n] = __builtin_amdgcn_mfma_f32_16x16x32_bf16(av0, bv0, acc[n], 0, 0, 0);
        const bf16x8 bv1 = ldb8(ib + ((size_t)ky1 * IWp + kxb) * 4);
        acc[n] = __builtin_amdgcn_mfma_f32_16x16x32_bf16(av1, bv1, acc[n], 0, 0, 0);
    }

    const float b0 = bias[lg * 4], b1 = bias[lg * 4 + 1],
                b2 = bias[lg * 4 + 2], b3 = bias[lg * 4 + 3];
    #pragma unroll
    for (int n = 0; n < 4; ++n) {
        const int px = pxb + n * 16 + lr;
        const int b = px >> HWsh;
        const int rem = px & ((1 << HWsh) - 1);
        const int oh = rem >> OWsh, ow = rem & (OW - 1);
        const f32x4 a = acc[n];
        u32x2 pk;
        pk[0] = (unsigned)f2bf(fmaxf(a[0] + b0, 0.f)) | ((unsigned)f2bf(fmaxf(a[1] + b1, 0.f)) << 16);
        pk[1] = (unsigned)f2bf(fmaxf(a[2] + b2, 0.f)) | ((unsigned)f2bf(fmaxf(a[3] + b3, 0.f)) << 16);
        u16* op = outP + (size_t)b * outSS + (((size_t)(oh + 1)) * OWp + (ow + 1)) * 16 + lg * 4;
        *(u32x2*)op = pk;
    }
}

// ---- tiled MFMA implicit-GEMM conv3x3, counted-vmcnt pipeline --------------
template<int BM, int BN, int NWM, int NWN, int S>
__global__ __launch_bounds__(256, 4)
void convg2_k(const u16* __restrict__ inP, const u16* __restrict__ Wp,
              const float* __restrict__ bias, u16* __restrict__ out,
              int IC_sh, int IWp, int inSS, int OW_sh, int OWp_o, int outSS,
              int pad_o, int Kreal, int nt, int Kpad, int relu, int n_pt, int OCtot)
{
    constexpr int MF = BM / (NWM * 16);
    constexpr int NF = BN / (NWN * 16);
    constexpr int ASLOT = BM * 4;
    constexpr int BSLOT = BN * 4;
    constexpr int AISS = ASLOT / 256;
    constexpr int BISS = BSLOT / 256;
    constexpr int NSTG = AISS + BISS;

    __shared__ __align__(16) u16 Ab[2][ASLOT * 8];
    __shared__ __align__(16) u16 Bb[2][BSLOT * 8];

    const int t    = threadIdx.x;
    const int wv   = t >> 6, lane = t & 63;
    const int lr   = lane & 15, lg = lane >> 4;
    const int wm   = wv / NWN, wn = wv % NWN;

    const int tilesPerB = (OCtot / BM) * n_pt;
    const int b  = blockIdx.x / tilesPerB;
    const int r0 = blockIdx.x - b * tilesPerB;
    const int mt = r0 / n_pt, pt = r0 - mt * n_pt;
    const int ocb = mt * BM, pxb = pt * BN;
    const int IC = 1 << IC_sh;
    const int OW = 1 << OW_sh;

    const u16* __restrict__ inb = inP + (size_t)b * inSS;

    const u16* agp[AISS];
    #pragma unroll
    for (int i = 0; i < AISS; ++i) {
        const int s = i * 256 + t;
        const int q = s / BM, rr = s - q * BM;
        agp[i] = Wp + (size_t)(ocb + rr) * Kpad + q * 8;
    }
    int bq[BISS]; const u16* bpx[BISS];
    #pragma unroll
    for (int i = 0; i < BISS; ++i) {
        const int s = i * 256 + t;
        const int q = s / BN, rr = s - q * BN;
        const int px = pxb + rr;
        const int oh = px >> OW_sh, ow = px & (OW - 1);
        bq[i] = q;
        bpx[i] = inb + ((size_t)(oh * S) * IWp + ow * S) * IC;
    }

    f32x4 acc[MF][NF] = {};

    auto STAGE = [&](int buf, int kb) {
        #pragma unroll
        for (int i = 0; i < AISS; ++i)
            gload16(agp[i] + kb, &Ab[buf][(size_t)(i * 256 + wv * 64) * 8]);
        #pragma unroll
        for (int i = 0; i < BISS; ++i) {
            const int k = kb + bq[i] * 8;
            const int tap = k >> IC_sh;
            const int ic = k & (IC - 1);
            const int ky = (tap * 11) >> 5, kx = tap - 3 * ky;
            const u16* g = bpx[i] + ((size_t)ky * IWp + kx) * IC + ic;
            if (k >= Kreal) g = inb;           // zero weights there; any in-bounds addr
            gload16(g, &Bb[buf][(size_t)(i * 256 + wv * 64) * 8]);
        }
    };

    STAGE(0, 0);
    int cur = 0;

    for (int ks = 0; ks < nt; ++ks) {
        if (ks + 1 < nt) {
            STAGE(cur ^ 1, (ks + 1) * 32);
            wait_vm<NSTG>();                    // retire current tile's loads only
        } else {
            wait_vm<0>();
        }
        bar_mem();                              // cur buffer ready for all waves

        bf16x8 af[MF], bf_[NF];
        #pragma unroll
        for (int m = 0; m < MF; ++m)
            af[m] = ldb8(&Ab[cur][(size_t)(lg * BM + wm * (MF * 16) + m * 16 + lr) * 8]);
        #pragma unroll
        for (int n = 0; n < NF; ++n)
            bf_[n] = ldb8(&Bb[cur][(size_t)(lg * BN + wn * (NF * 16) + n * 16 + lr) * 8]);
        #pragma unroll
        for (int m = 0; m < MF; ++m)
            #pragma unroll
            for (int n = 0; n < NF; ++n)
                acc[m][n] = __builtin_amdgcn_mfma_f32_16x16x32_bf16(af[m], bf_[n], acc[m][n], 0, 0, 0);

        bar_mem();                              // all reads of cur done
        cur ^= 1;
    }

    #pragma unroll
    for (int m = 0; m < MF; ++m) {
        const int oc0 = ocb + wm * (MF * 16) + m * 16 + lg * 4;
        const float b0 = bias[oc0], b1 = bias[oc0 + 1], b2 = bias[oc0 + 2], b3 = bias[oc0 + 3];
        #pragma unroll
        for (int n = 0; n < NF; ++n) {
            const int px = pxb + wn * (NF * 16) + n * 16 + lr;
            const int oh = px >> OW_sh, ow = px & (OW - 1);
            const f32x4 a = acc[m][n];
            float v0 = a[0] + b0, v1 = a[1] + b1, v2 = a[2] + b2, v3 = a[3] + b3;
            if (relu) {
                v0 = fmaxf(v0, 0.f); v1 = fmaxf(v1, 0.f);
                v2 = fmaxf(v2, 0.f); v3 = fmaxf(v3, 0.f);
            }
            u32x2 pk;
            pk[0] = (unsigned)f2bf(v0) | ((unsigned)f2bf(v1) << 16);
            pk[1] = (unsigned)f2bf(v2) | ((unsigned)f2bf(v3) << 16);
            u16* op = out + (size_t)b * outSS +
                      (((size_t)(oh + pad_o)) * OWp_o + (ow + pad_o)) * (size_t)OCtot + oc0;
            *(u32x2*)op = pk;
        }
    }
}

// ---- xcorr as batched MFMA GEMM --------------------------------------------
__global__ __launch_bounds__(256)
void xcmf_k(const u16* __restrict__ ffm, const u16* __restrict__ cfm,
            float* __restrict__ R)
{
    const int w    = blockIdx.x * 4 + (threadIdx.x >> 6);   // 1600 waves
    const int lane = threadIdx.x & 63;
    const int lr   = lane & 15, lg = lane >> 4;
    const int b  = w / 25;
    const int tp = w - b * 25;

    const int col0 = tp * 32 + lr;
    const int col1 = col0 + 16;
    const int y0 = col0 / 25, x0 = col0 - y0 * 25;
    const int y1 = col1 / 25, x1 = col1 - y1 * 25;

    const u16* fb = ffm + (size_t)b * 262144;
    const u16* f0 = fb + ((size_t)y0 * 32 + x0) * 256 + lg * 8;
    const u16* f1 = fb + ((size_t)y1 * 32 + x1) * 256 + lg * 8;
    const u16* ab = cfm + (size_t)b * 16384 + (size_t)lr * 2048 + lg * 8;
    const bool arow = (lr < 8);

    f32x4 acc0 = {}, acc1 = {};
    #pragma unroll 4
    for (int kb = 0; kb < 2048; kb += 32) {
        const bf16x8 av = arow ? ldb8(ab + kb) : zerob8();
        const bf16x8 bv0 = ldb8(f0 + kb);
        const bf16x8 bv1 = ldb8(f1 + kb);
        acc0 = __builtin_amdgcn_mfma_f32_16x16x32_bf16(av, bv0, acc0, 0, 0, 0);
        acc1 = __builtin_amdgcn_mfma_f32_16x16x32_bf16(av, bv1, acc1, 0, 0, 0);
    }

    if (lg < 2) {
        float* rb = R + (size_t)b * 6400;
        #pragma unroll
        for (int j = 0; j < 4; ++j) {
            const int d = lg * 4 + j;
            rb[(size_t)d * 800 + col0] = acc0[j];
            rb[(size_t)d * 800 + col1] = acc1[j];
        }
    }
}

// ---- diagonal-band reduce --------------------------------------------------
__global__ __launch_bounds__(256)
void xred_k(const float* __restrict__ R, float* __restrict__ part)
{
    const int i = blockIdx.x * 256 + threadIdx.x;
    if (i >= 40000) return;
    const int b = i / 625;
    const int o = i - b * 625;
    const float* rb = R + (size_t)b * 6400 + o;
    float v = 0.f;
    #pragma unroll
    for (int d = 0; d < 8; ++d) v += rb[(size_t)d * 800 + d * 25];
    part[i] = v;
}

// ---- BatchNorm over all 40000 elements -------------------------------------
__global__ __launch_bounds__(1024)
void bn_k(const float* __restrict__ rmap, const float* __restrict__ gamma,
          const float* __restrict__ beta, float* __restrict__ out)
{
    const int N = 40000;
    const int tid = threadIdx.x;
    __shared__ float rs[1024], rq[1024];
    __shared__ float mean_s, inv_s;
    float s = 0.f, q = 0.f;
    for (int i = tid; i < N; i += 1024) {
        const float v = rmap[i];
        s += v; q += v * v;
    }
    rs[tid] = s; rq[tid] = q;
    __syncthreads();
    for (int off = 512; off > 0; off >>= 1) {
        if (tid < off) { rs[tid] += rs[tid + off]; rq[tid] += rq[tid + off]; }
        __syncthreads();
    }
    if (tid == 0) {
        const float m = rs[0] / (float)N;
        mean_s = m;
        inv_s = rsqrtf(rq[0] / (float)N - m * m + 1e-5f);
    }
    __syncthreads();
    const float g = gamma[0], bt = beta[0];
    for (int i = tid; i < N; i += 1024)
        out[i] = (rmap[i] - mean_s) * inv_s * g + bt;
}

// ---------------------------------------------------------------------------

extern "C" void kernel_launch(void* const* d_in, const int* in_sizes, int n_in,
                              void* d_out, int out_size, void* d_ws, size_t ws_size,
                              hipStream_t stream)
{
    (void)in_sizes; (void)n_in; (void)out_size; (void)ws_size;
    const float* crop  = (const float*)d_in[0];
    const float* frame = (const float*)d_in[1];
    const float* W[5]; const float* bb[5];
    for (int i = 0; i < 5; ++i) { W[i] = (const float*)d_in[2 + 2*i]; bb[i] = (const float*)d_in[3 + 2*i]; }
    const float* gamma = (const float*)d_in[12];
    const float* beta  = (const float*)d_in[13];
    float* out = (float*)d_out;

    unsigned char* ws = (unsigned char*)d_ws;
    // frame pipeline (sizes in BYTES, all verified = elements*2):
    u16*   f0b  = (u16*)(ws + 0);             // [64][130][130][4]   8,652,800 B (dead after fL1)
    u16*   f1p  = (u16*)(ws + 8652800);       // [64][66][66][16]    8,921,088 B (dead after fL2)
    u16*   f2p  = (u16*)(ws + 17573888);      // [64][66][66][64]   35,684,352 B (dead after fL3)
    u16*   f3p  = (u16*)(ws + 53258240);      // [64][34][34][128]  18,939,904 B  <- FIXED size
    u16*   ffm  = (u16*)(ws + 0);             // [64][32][32][256]  33,554,432 B (aliases dead f0b..f2p)
    // crop pipeline + weights + xcorr after f3p (ends 72,198,144):
    u16*   c0b  = (u16*)(ws + 72198144);      // [64][34][34][4]       591,872 B
    u16*   c1p  = (u16*)(ws + 72790016);      // [64][18][18][16]      663,552 B
    u16*   c2p  = (u16*)(ws + 73453568);      // [64][18][18][64]    2,654,208 B
    u16*   c3p  = (u16*)(ws + 76107776);      // [64][10][10][128]   1,638,400 B
    u16*   cfm  = (u16*)(ws + 77746176);      // [64][8][8][256]     2,097,152 B
    u16*   Wc1  = (u16*)(ws + 79843328);      // [16][64]                2,048 B
    u16*   Wp2  = (u16*)(ws + 79845376);      // [64][160]              20,480 B
    u16*   Wp3  = (u16*)(ws + 79865856);      // [128][576]            147,456 B
    u16*   Wp4  = (u16*)(ws + 80013312);      // [256][1152]           589,824 B
    float* Rbuf = (float*)(ws + 80603136);    // [64][8][800] f32    1,638,400 B
    float* part = (float*)(ws + 82241536);    // [40000] f32           160,000 B
    // total 82,401,536 B (< 105.5 MB proven available in R1)

    // ---- one merged halo-zero launch ----
    HZall hz;
    const unsigned long long ptrs[8] = {(unsigned long long)c0b, (unsigned long long)c1p,
        (unsigned long long)c2p, (unsigned long long)c3p, (unsigned long long)f0b,
        (unsigned long long)f1p, (unsigned long long)f2p, (unsigned long long)f3p};
    const int Hps[8] = {34, 18, 18, 10, 130, 66, 66, 34};
    const int w8s[8] = {1, 4, 16, 32, 1, 4, 16, 32};
    int cum = 0;
    for (int i = 0; i < 8; ++i) {
        hz.d[i].ptr = ptrs[i]; hz.d[i].B = 64; hz.d[i].Hp = Hps[i];
        hz.d[i].Wpx = Hps[i]; hz.d[i].w8 = w8s[i]; hz.d[i].cum = cum;
        cum += 64 * (2 * Hps[i] + 2 * (Hps[i] - 2)) * w8s[i];
    }
    hz.total = cum;
    haloz_k<<<1024, 256, 0, stream>>>(hz);

    // ---- one merged weight-pack launch ----
    packall_k<<<1484, 256, 0, stream>>>(W[1], W[2], W[3], W[4], Wc1, Wp2, Wp3, Wp4);

    // ---- crop encoder: 64x64 ->32 ->16 ->16 ->8 ->8 ----
    conv0_k<<<64, 256, 0, stream>>>(crop, W[0], bb[0], c0b, 64, 64, 64, 32, 32);
    conv1g_k<4, 8><<<64, 256, 0, stream>>>(c0b, Wc1, bb[1], c1p, 34, 4624, 18, 5184);
    convg2_k< 64,256,1,4,1><<< 64, 256, 0, stream>>>(c1p, Wp2, bb[2], c2p, 4, 18,  5184, 4, 18, 20736, 1, 144,  5,  160, 1, 1,  64);
    convg2_k<128, 64,4,1,2><<< 64, 256, 0, stream>>>(c2p, Wp3, bb[3], c3p, 6, 18, 20736, 3, 10, 12800, 1, 576, 18,  576, 1, 1, 128);
    convg2_k<256, 64,4,1,1><<< 64, 256, 0, stream>>>(c3p, Wp4, bb[4], cfm, 7, 10, 12800, 3,  8, 16384, 0, 1152, 36, 1152, 0, 1, 256);

    // ---- frame encoder: 256x256 ->128 ->64 ->64 ->32 ->32 ----
    conv0_k<<<1024, 256, 0, stream>>>(frame, W[0], bb[0], f0b, 64, 256, 256, 128, 128);
    conv1g_k<6, 12><<<1024, 256, 0, stream>>>(f0b, Wc1, bb[1], f1p, 130, 67600, 66, 69696);
    convg2_k< 64,256,1,4,1><<<1024, 256, 0, stream>>>(f1p, Wp2, bb[2], f2p, 4, 66,  69696, 6, 66, 278784, 1, 144,  5,  160, 1, 16,  64);
    convg2_k<128,128,2,2,2><<< 512, 256, 0, stream>>>(f2p, Wp3, bb[3], f3p, 6, 66, 278784, 5, 34, 147968, 1, 576, 18,  576, 1, 8, 128);
    convg2_k<128,128,2,2,1><<<1024, 256, 0, stream>>>(f3p, Wp4, bb[4], ffm, 7, 34, 147968, 5, 32, 262144, 0, 1152, 36, 1152, 0, 8, 256);

    // ---- xcorr (MFMA) + band-reduce + BN ----
    xcmf_k<<<400, 256, 0, stream>>>(ffm, cfm, Rbuf);
    xred_k<<<157, 256, 0, stream>>>(Rbuf, part);
    bn_k<<<1, 1024, 0, stream>>>(part, gamma, beta, out);
}